// Round 15
// baseline (132.002 us; speedup 1.0000x reference)
//
#include <hip/hip_runtime.h>
#include <hip/hip_fp16.h>
#include <math.h>

#define C 128
#define BSHIFT 9        // bucket width = 512 nodes
#define BWIDTH 512
#define NBMAX 256       // >= ceil(100000/512)=196
#define COLBITS 17      // N=100000 < 2^17; ebuf packs (lrow<<17)|col
#define P2CHUNK 8192    // edges per p2 block (16/thread, 512 threads)
#define P3CAP 10240     // LDS staging capacity for one bucket (max count ~8500)
#define CAP 9216        // fixed per-bucket segment capacity (mean 8192 + 11.6 sigma)
#define APITCH 136      // fp16 pitch for LDS agg tile: 272B rows -> 2-way conflicts (free)

typedef _Float16 v8hf __attribute__((ext_vector_type(8)));
typedef float v4f __attribute__((ext_vector_type(4)));

// ---- 1. scatter edges into bucket-segmented ebuf (LDS sort) + x/W->fp16 tail ----
// gcur starts 0 (memset); segment base = b*CAP + old cursor; gcur ends = count.
__global__ __launch_bounds__(512) void p2_scatter_kernel(const int* __restrict__ rowI,
                                                         const int* __restrict__ colI,
                                                         int* __restrict__ gcur,
                                                         unsigned* __restrict__ ebuf, int E,
                                                         const float4* __restrict__ x4,
                                                         __half2* __restrict__ xh2, int N,
                                                         const float4* __restrict__ W4,
                                                         __half2* __restrict__ Wh2,
                                                         int wtotal4) {
    __shared__ int cnt[NBMAX];
    __shared__ int sc[NBMAX];                 // scan -> reused as lstart
    __shared__ int delta[NBMAX];              // global base - lstart
    __shared__ unsigned sorted[P2CHUNK];      // 32 KB
    __shared__ unsigned char bkt[P2CHUNK];    // 8 KB
    const int t = threadIdx.x;
    if (t < NBMAX) cnt[t] = 0;
    __syncthreads();
    const int e0 = blockIdx.x * P2CHUNK;
    int ranks[16];
#pragma unroll
    for (int k = 0; k < 16; ++k) {
        int e = e0 + k * 512 + t;
        if (e < E) ranks[k] = atomicAdd(&cnt[rowI[e] >> BSHIFT], 1);
    }
    __syncthreads();
    if (t < NBMAX) sc[t] = cnt[t];
    __syncthreads();
    for (int o = 1; o < NBMAX; o <<= 1) {     // Hillis-Steele inclusive (guarded)
        int v = (t < NBMAX && t >= o) ? sc[t - o] : 0;
        __syncthreads();
        if (t < NBMAX) sc[t] += v;
        __syncthreads();
    }
    if (t < NBMAX) {
        int c = cnt[t];
        int ls = sc[t] - c;                   // local exclusive start
        int gb = c ? (t * CAP + atomicAdd(&gcur[t], c)) : 0;
        delta[t] = gb - ls;
        sc[t] = ls;                           // sc now holds lstart
    }
    __syncthreads();
#pragma unroll
    for (int k = 0; k < 16; ++k) {
        int e = e0 + k * 512 + t;
        if (e < E) {
            int r = rowI[e];                  // L1/L2-hot re-read
            unsigned cc = (unsigned)colI[e];
            int b = r >> BSHIFT;
            int lp = sc[b] + ranks[k];
            sorted[lp] = ((unsigned)(r & (BWIDTH - 1)) << COLBITS) | cc;
            bkt[lp] = (unsigned char)b;
        }
    }
    __syncthreads();
    int total = E - e0; if (total > P2CHUNK) total = P2CHUNK;
#pragma unroll
    for (int k = 0; k < 16; ++k) {            // linear LDS -> coalesced global runs
        int i = k * 512 + t;
        if (i < total) ebuf[delta[bkt[i]] + i] = sorted[i];
    }

    // ---- fused x -> fp16 (UNSCALED) and W -> fp16 (grid-stride tail) ----
    int totalX4 = N * 32;                     // 32 float4 per row
    int totalConv = totalX4 + wtotal4;
    for (int i = blockIdx.x * 512 + t; i < totalConv; i += gridDim.x * 512) {
        if (i < totalX4) {
            float4 v = x4[i];
            xh2[i * 2]     = __floats2half2_rn(v.x, v.y);
            xh2[i * 2 + 1] = __floats2half2_rn(v.z, v.w);
        } else {
            int j = i - totalX4;
            float4 v = W4[j];
            Wh2[j * 2]     = __floats2half2_rn(v.x, v.y);
            Wh2[j * 2 + 1] = __floats2half2_rn(v.z, v.w);
        }
    }
}

// ---- 2. per-bucket place: LDS-staged segment, wave-scan, csr stream ----
// NB(196) < 256 CUs -> 1 block/CU; ~82KB LDS is free here.
// Emits offs_start/offs_end[node], inv[node] = rsqrt(deg+1), csr.
__global__ __launch_bounds__(512) void p3_place_kernel(const unsigned* __restrict__ ebuf,
                                                       const int* __restrict__ gcur,
                                                       int* __restrict__ offs_start,
                                                       int* __restrict__ offs_end,
                                                       float* __restrict__ inv,
                                                       int* __restrict__ csr, int N) {
    __shared__ unsigned eb[P3CAP];            // 40 KB staged segment
    __shared__ int sortedCol[P3CAP];          // 40 KB
    __shared__ int cnt[BWIDTH];
    __shared__ int woff[8];
    const int b = blockIdx.x;
    const int t = threadIdx.x;
    const int lane = t & 63;
    const int wv = t >> 6;
    const int rowBase = b << BSHIFT;
    const int eS = b * CAP;
    int len = gcur[b];                        // bucket count (<= CAP < P3CAP)
    if (len > P3CAP) len = P3CAP;

    cnt[t] = 0;
    __syncthreads();
    for (int i = t; i < len; i += 512) {      // stage + histogram, single global read
        unsigned rc = ebuf[eS + i];
        eb[i] = rc;
        atomicAdd(&cnt[rc >> COLBITS], 1);
    }
    __syncthreads();
    int myCnt = cnt[t];
    int v = myCnt;                            // wave-inclusive scan (shfl_up)
#pragma unroll
    for (int o = 1; o < 64; o <<= 1) {
        int u = __shfl_up(v, o, 64);
        if (lane >= o) v += u;
    }
    if (lane == 63) woff[wv] = v;
    __syncthreads();
    if (t == 0) {                             // serial scan of 8 wave totals
        int s = 0;
#pragma unroll
        for (int w = 0; w < 8; ++w) { int u = woff[w]; woff[w] = s; s += u; }
    }
    __syncthreads();
    int incl = v + woff[wv];                  // inclusive prefix over 512 bins
    int node = rowBase + t;
    if (node < N) {
        offs_start[node] = eS + incl - myCnt;
        offs_end[node]   = eS + incl;
        inv[node] = rsqrtf((float)myCnt + 1.0f);
    }
    cnt[t] = incl - myCnt;                    // local exclusive start -> cursor
    __syncthreads();
    for (int i = t; i < len; i += 512) {
        unsigned rc = eb[i];
        int slot = atomicAdd(&cnt[rc >> COLBITS], 1);
        sortedCol[slot] = (int)(rc & ((1u << COLBITS) - 1));
    }
    __syncthreads();
    for (int i = t; i < len; i += 512)        // pure streaming write
        csr[eS + i] = sortedCol[i];
}

// ---- 3. fused gather + MFMA GEMM (256 thr = 16 nodes x 16 lanes) ----
// Phase 1: a += inv[c] * xh[c] per edge (fmaf); scale by inv[n]; fp16 row ->
// LDS agg. Phase 2: 4 waves compute out[16][128] = agg @ Wh^T (16x16x32 f16).
// A lane: row=l&15, k=(l>>4)*8+i (+kk*32); D: col=lane&15, row=(lane>>4)*4+reg.
#define ACC4F(vv, sI)                                              \
    {                                                              \
        const __half2* p_ = (const __half2*)&(vv);                 \
        _Pragma("unroll")                                          \
        for (int q = 0; q < 4; ++q) {                              \
            float2 f_ = __half22float2(p_[q]);                     \
            a[2 * q]     = fmaf(f_.x, (sI), a[2 * q]);             \
            a[2 * q + 1] = fmaf(f_.y, (sI), a[2 * q + 1]);         \
        }                                                          \
    }

__global__ __launch_bounds__(256) void gather_mm_kernel(const float4* __restrict__ xh4,
                                                        const int* __restrict__ offs_start,
                                                        const int* __restrict__ offs_end,
                                                        const int* __restrict__ csr,
                                                        const float* __restrict__ inv,
                                                        const _Float16* __restrict__ Wh,
                                                        float* __restrict__ out, int N) {
    __shared__ _Float16 agg[16][APITCH];      // 4.25 KB
    const int tid = threadIdx.x;
    const int base = blockIdx.x * 16;
    const int r = tid >> 4;                   // block-local node 0..15
    const int c16 = tid & 15;                 // 16B chunk within row
    const int node = base + r;

    float a[8] = {0, 0, 0, 0, 0, 0, 0, 0};
    float invn = 0.0f;
    if (node < N) {
        int s = __builtin_nontemporal_load(&offs_start[node]);
        int e = __builtin_nontemporal_load(&offs_end[node]);
        invn = inv[node];
        {   // self term
            float4 h = xh4[(size_t)node * 16 + c16];
            ACC4F(h, invn)
        }
        int j = s;
        for (; j + 4 <= e; j += 4) {
            int c0 = __builtin_nontemporal_load(&csr[j]);
            int c1 = __builtin_nontemporal_load(&csr[j + 1]);
            int c2 = __builtin_nontemporal_load(&csr[j + 2]);
            int c3 = __builtin_nontemporal_load(&csr[j + 3]);
            float i0 = inv[c0], i1 = inv[c1], i2 = inv[c2], i3 = inv[c3];
            float4 v0 = xh4[(size_t)c0 * 16 + c16];
            float4 v1 = xh4[(size_t)c1 * 16 + c16];
            float4 v2 = xh4[(size_t)c2 * 16 + c16];
            float4 v3 = xh4[(size_t)c3 * 16 + c16];
            ACC4F(v0, i0) ACC4F(v1, i1) ACC4F(v2, i2) ACC4F(v3, i3)
        }
        for (; j < e; ++j) {
            int c = __builtin_nontemporal_load(&csr[j]);
            float ic = inv[c];
            float4 v = xh4[(size_t)c * 16 + c16];
            ACC4F(v, ic)
        }
#pragma unroll
        for (int q = 0; q < 8; ++q) a[q] *= invn;
    }
    {
        __half2 hh[4];
#pragma unroll
        for (int q = 0; q < 4; ++q) hh[q] = __floats2half2_rn(a[2 * q], a[2 * q + 1]);
        *(float4*)&agg[r][c16 * 8] = *(const float4*)hh;   // 16B, 2-way banks (free)
    }
    __syncthreads();

    // ---- MFMA phase: wave w computes col-tiles t = 2w, 2w+1 ----
    const int wave = tid >> 6;
    const int lane = tid & 63;
    const int rr = lane & 15;
    const int kg = lane >> 4;

    v8hf av[4];
#pragma unroll
    for (int kk = 0; kk < 4; ++kk)
        av[kk] = *(const v8hf*)&agg[rr][kg * 8 + kk * 32];

#pragma unroll
    for (int ti = 0; ti < 2; ++ti) {
        const int t = wave * 2 + ti;
        v4f acc = {0.0f, 0.0f, 0.0f, 0.0f};
        const v8hf* bp = (const v8hf*)(Wh + (size_t)(t * 16 + rr) * C + kg * 8);
#pragma unroll
        for (int kk = 0; kk < 4; ++kk)
            acc = __builtin_amdgcn_mfma_f32_16x16x32_f16(av[kk], bp[kk * 4], acc, 0, 0, 0);
#pragma unroll
        for (int reg = 0; reg < 4; ++reg) {
            int orow = base + kg * 4 + reg;
            if (orow < N) out[(size_t)orow * C + t * 16 + rr] = acc[reg];
        }
    }
}

extern "C" void kernel_launch(void* const* d_in, const int* in_sizes, int n_in,
                              void* d_out, int out_size, void* d_ws, size_t ws_size,
                              hipStream_t stream) {
    const float* x  = (const float*)d_in[0];
    const int*   ei = (const int*)d_in[1];
    const float* W  = (const float*)d_in[2];
    float* out = (float*)d_out;

    const int N = in_sizes[0] / C;
    const int E = in_sizes[1] / 2;
    const int* rowI = ei;        // edge_index[0]
    const int* colI = ei + E;    // edge_index[1]

    const int NB = (N + BWIDTH - 1) / BWIDTH;     // 196 for N=100000

    // workspace carve-up (256B-aligned regions)
    char* ws = (char*)d_ws;
    size_t off = 0;
    auto carve = [&](size_t bytes) -> void* {
        off = (off + 255) & ~(size_t)255;
        void* p = ws + off;
        off += bytes;
        return p;
    };
    int*      gcur       = (int*)carve((size_t)NBMAX * 4);
    int*      offs_start = (int*)carve((size_t)N * 4);
    int*      offs_end   = (int*)carve((size_t)N * 4);
    float*    inv        = (float*)carve((size_t)N * 4);
    int*      csr        = (int*)carve((size_t)NB * CAP * 4);
    __half2*  xh         = (__half2*)carve((size_t)N * C * 2);
    unsigned* ebuf       = (unsigned*)carve((size_t)NB * CAP * 4);
    __half2*  Wh         = (__half2*)carve((size_t)C * C * 2);

    hipMemsetAsync(gcur, 0, (size_t)NBMAX * 4, stream);

    int wtotal4 = C * C / 4;                  // 4096 float4
    int nChunks = (E + P2CHUNK - 1) / P2CHUNK;
    p2_scatter_kernel<<<nChunks, 512, 0, stream>>>(rowI, colI, gcur, ebuf, E,
                                                   (const float4*)x, xh, N,
                                                   (const float4*)W, Wh, wtotal4);
    p3_place_kernel<<<NB, 512, 0, stream>>>(ebuf, gcur, offs_start, offs_end, inv, csr, N);

    gather_mm_kernel<<<(N + 15) / 16, 256, 0, stream>>>((const float4*)xh, offs_start,
                                                        offs_end, csr, inv,
                                                        (const _Float16*)Wh, out, N);
}

// Round 16
// 124.578 us; speedup vs baseline: 1.0596x; 1.0596x over previous
//
#include <hip/hip_runtime.h>
#include <hip/hip_fp16.h>
#include <math.h>

#define C 128
#define BSHIFT 9        // bucket width = 512 nodes
#define BWIDTH 512
#define NBMAX 256       // >= ceil(100000/512)=196
#define COLBITS 17      // N=100000 < 2^17; ebuf packs (lrow<<17)|col
#define P2CHUNK 8192    // edges per p2 block (16/thread, 512 threads)
#define P3CAP 10240     // LDS staging capacity for one bucket (max count ~8500)
#define CAP 9216        // fixed per-bucket segment capacity (mean 8192 + 11.6 sigma)
#define APITCH 136      // fp16 pitch for LDS agg tile: 272B rows -> 2-way conflicts (free)

typedef _Float16 v8hf __attribute__((ext_vector_type(8)));
typedef float v4f __attribute__((ext_vector_type(4)));

// ---- 1. scatter edges into bucket-segmented ebuf (LDS sort) + x/W->fp16 tail ----
// gcur starts 0 (memset); segment base = b*CAP + old cursor; gcur ends = count.
__global__ __launch_bounds__(512) void p2_scatter_kernel(const int* __restrict__ rowI,
                                                         const int* __restrict__ colI,
                                                         int* __restrict__ gcur,
                                                         unsigned* __restrict__ ebuf, int E,
                                                         const float4* __restrict__ x4,
                                                         __half2* __restrict__ xh2, int N,
                                                         const float4* __restrict__ W4,
                                                         __half2* __restrict__ Wh2,
                                                         int wtotal4) {
    __shared__ int cnt[NBMAX];
    __shared__ int sc[NBMAX];                 // scan -> reused as lstart
    __shared__ int delta[NBMAX];              // global base - lstart
    __shared__ unsigned sorted[P2CHUNK];      // 32 KB
    __shared__ unsigned char bkt[P2CHUNK];    // 8 KB
    const int t = threadIdx.x;
    if (t < NBMAX) cnt[t] = 0;
    __syncthreads();
    const int e0 = blockIdx.x * P2CHUNK;
    int ranks[16];
#pragma unroll
    for (int k = 0; k < 16; ++k) {
        int e = e0 + k * 512 + t;
        if (e < E) ranks[k] = atomicAdd(&cnt[rowI[e] >> BSHIFT], 1);
    }
    __syncthreads();
    if (t < NBMAX) sc[t] = cnt[t];
    __syncthreads();
    for (int o = 1; o < NBMAX; o <<= 1) {     // Hillis-Steele inclusive (guarded)
        int v = (t < NBMAX && t >= o) ? sc[t - o] : 0;
        __syncthreads();
        if (t < NBMAX) sc[t] += v;
        __syncthreads();
    }
    if (t < NBMAX) {
        int c = cnt[t];
        int ls = sc[t] - c;                   // local exclusive start
        int gb = c ? (t * CAP + atomicAdd(&gcur[t], c)) : 0;
        delta[t] = gb - ls;
        sc[t] = ls;                           // sc now holds lstart
    }
    __syncthreads();
#pragma unroll
    for (int k = 0; k < 16; ++k) {
        int e = e0 + k * 512 + t;
        if (e < E) {
            int r = rowI[e];                  // L1/L2-hot re-read
            unsigned cc = (unsigned)colI[e];
            int b = r >> BSHIFT;
            int lp = sc[b] + ranks[k];
            sorted[lp] = ((unsigned)(r & (BWIDTH - 1)) << COLBITS) | cc;
            bkt[lp] = (unsigned char)b;
        }
    }
    __syncthreads();
    int total = E - e0; if (total > P2CHUNK) total = P2CHUNK;
#pragma unroll
    for (int k = 0; k < 16; ++k) {            // linear LDS -> coalesced global runs
        int i = k * 512 + t;
        if (i < total) ebuf[delta[bkt[i]] + i] = sorted[i];
    }

    // ---- fused x -> fp16 (UNSCALED) and W -> fp16 (grid-stride tail) ----
    int totalX4 = N * 32;                     // 32 float4 per row
    int totalConv = totalX4 + wtotal4;
    for (int i = blockIdx.x * 512 + t; i < totalConv; i += gridDim.x * 512) {
        if (i < totalX4) {
            float4 v = x4[i];
            xh2[i * 2]     = __floats2half2_rn(v.x, v.y);
            xh2[i * 2 + 1] = __floats2half2_rn(v.z, v.w);
        } else {
            int j = i - totalX4;
            float4 v = W4[j];
            Wh2[j * 2]     = __floats2half2_rn(v.x, v.y);
            Wh2[j * 2 + 1] = __floats2half2_rn(v.z, v.w);
        }
    }
}

// ---- 2. per-bucket place: LDS-staged segment, wave-scan, csr stream ----
// NB(196) < 256 CUs -> 1 block/CU; ~82KB LDS is free here.
// Emits offs_start/offs_end[node], inv[node] = rsqrt(deg+1), csr.
__global__ __launch_bounds__(512) void p3_place_kernel(const unsigned* __restrict__ ebuf,
                                                       const int* __restrict__ gcur,
                                                       int* __restrict__ offs_start,
                                                       int* __restrict__ offs_end,
                                                       float* __restrict__ inv,
                                                       int* __restrict__ csr, int N) {
    __shared__ unsigned eb[P3CAP];            // 40 KB staged segment
    __shared__ int sortedCol[P3CAP];          // 40 KB
    __shared__ int cnt[BWIDTH];
    __shared__ int woff[8];
    const int b = blockIdx.x;
    const int t = threadIdx.x;
    const int lane = t & 63;
    const int wv = t >> 6;
    const int rowBase = b << BSHIFT;
    const int eS = b * CAP;
    int len = gcur[b];                        // bucket count (<= CAP < P3CAP)
    if (len > P3CAP) len = P3CAP;

    cnt[t] = 0;
    __syncthreads();
    for (int i = t; i < len; i += 512) {      // stage + histogram, single global read
        unsigned rc = ebuf[eS + i];
        eb[i] = rc;
        atomicAdd(&cnt[rc >> COLBITS], 1);
    }
    __syncthreads();
    int myCnt = cnt[t];
    int v = myCnt;                            // wave-inclusive scan (shfl_up)
#pragma unroll
    for (int o = 1; o < 64; o <<= 1) {
        int u = __shfl_up(v, o, 64);
        if (lane >= o) v += u;
    }
    if (lane == 63) woff[wv] = v;
    __syncthreads();
    if (t == 0) {                             // serial scan of 8 wave totals
        int s = 0;
#pragma unroll
        for (int w = 0; w < 8; ++w) { int u = woff[w]; woff[w] = s; s += u; }
    }
    __syncthreads();
    int incl = v + woff[wv];                  // inclusive prefix over 512 bins
    int node = rowBase + t;
    if (node < N) {
        offs_start[node] = eS + incl - myCnt;
        offs_end[node]   = eS + incl;
        inv[node] = rsqrtf((float)myCnt + 1.0f);
    }
    cnt[t] = incl - myCnt;                    // local exclusive start -> cursor
    __syncthreads();
    for (int i = t; i < len; i += 512) {
        unsigned rc = eb[i];
        int slot = atomicAdd(&cnt[rc >> COLBITS], 1);
        sortedCol[slot] = (int)(rc & ((1u << COLBITS) - 1));
    }
    __syncthreads();
    for (int i = t; i < len; i += 512)        // pure streaming write
        csr[eS + i] = sortedCol[i];
}

// ---- 3. fused gather + MFMA GEMM (256 thr = 16 nodes x 16 lanes) ----
// Phase 1: a += inv[c] * xh[c] per edge (fmaf); scale by inv[n]; fp16 row ->
// LDS agg. Phase 2: 4 waves compute out[16][128] = agg @ Wh^T (16x16x32 f16).
// A lane: row=l&15, k=(l>>4)*8+i (+kk*32); D: col=lane&15, row=(lane>>4)*4+reg.
#define ACC4F(vv, sI)                                              \
    {                                                              \
        const __half2* p_ = (const __half2*)&(vv);                 \
        _Pragma("unroll")                                          \
        for (int q = 0; q < 4; ++q) {                              \
            float2 f_ = __half22float2(p_[q]);                     \
            a[2 * q]     = fmaf(f_.x, (sI), a[2 * q]);             \
            a[2 * q + 1] = fmaf(f_.y, (sI), a[2 * q + 1]);         \
        }                                                          \
    }

__global__ __launch_bounds__(256) void gather_mm_kernel(const float4* __restrict__ xh4,
                                                        const int* __restrict__ offs_start,
                                                        const int* __restrict__ offs_end,
                                                        const int* __restrict__ csr,
                                                        const float* __restrict__ inv,
                                                        const _Float16* __restrict__ Wh,
                                                        float* __restrict__ out, int N) {
    __shared__ _Float16 agg[16][APITCH];      // 4.25 KB
    const int tid = threadIdx.x;
    const int base = blockIdx.x * 16;
    const int r = tid >> 4;                   // block-local node 0..15
    const int c16 = tid & 15;                 // 16B chunk within row
    const int node = base + r;

    float a[8] = {0, 0, 0, 0, 0, 0, 0, 0};
    float invn = 0.0f;
    if (node < N) {
        int s = offs_start[node];
        int e = offs_end[node];
        invn = inv[node];
        {   // self term
            float4 h = xh4[(size_t)node * 16 + c16];
            ACC4F(h, invn)
        }
        int j = s;
        for (; j + 4 <= e; j += 4) {
            int c0 = csr[j], c1 = csr[j + 1], c2 = csr[j + 2], c3 = csr[j + 3];
            float i0 = inv[c0], i1 = inv[c1], i2 = inv[c2], i3 = inv[c3];
            float4 v0 = xh4[(size_t)c0 * 16 + c16];
            float4 v1 = xh4[(size_t)c1 * 16 + c16];
            float4 v2 = xh4[(size_t)c2 * 16 + c16];
            float4 v3 = xh4[(size_t)c3 * 16 + c16];
            ACC4F(v0, i0) ACC4F(v1, i1) ACC4F(v2, i2) ACC4F(v3, i3)
        }
        for (; j < e; ++j) {
            int c = csr[j];
            float ic = inv[c];
            float4 v = xh4[(size_t)c * 16 + c16];
            ACC4F(v, ic)
        }
#pragma unroll
        for (int q = 0; q < 8; ++q) a[q] *= invn;
    }
    {
        __half2 hh[4];
#pragma unroll
        for (int q = 0; q < 4; ++q) hh[q] = __floats2half2_rn(a[2 * q], a[2 * q + 1]);
        *(float4*)&agg[r][c16 * 8] = *(const float4*)hh;   // 16B, 2-way banks (free)
    }
    __syncthreads();

    // ---- MFMA phase: wave w computes col-tiles t = 2w, 2w+1 ----
    const int wave = tid >> 6;
    const int lane = tid & 63;
    const int rr = lane & 15;
    const int kg = lane >> 4;

    v8hf av[4];
#pragma unroll
    for (int kk = 0; kk < 4; ++kk)
        av[kk] = *(const v8hf*)&agg[rr][kg * 8 + kk * 32];

#pragma unroll
    for (int ti = 0; ti < 2; ++ti) {
        const int t = wave * 2 + ti;
        v4f acc = {0.0f, 0.0f, 0.0f, 0.0f};
        const v8hf* bp = (const v8hf*)(Wh + (size_t)(t * 16 + rr) * C + kg * 8);
#pragma unroll
        for (int kk = 0; kk < 4; ++kk)
            acc = __builtin_amdgcn_mfma_f32_16x16x32_f16(av[kk], bp[kk * 4], acc, 0, 0, 0);
#pragma unroll
        for (int reg = 0; reg < 4; ++reg) {
            int orow = base + kg * 4 + reg;
            if (orow < N) out[(size_t)orow * C + t * 16 + rr] = acc[reg];
        }
    }
}

extern "C" void kernel_launch(void* const* d_in, const int* in_sizes, int n_in,
                              void* d_out, int out_size, void* d_ws, size_t ws_size,
                              hipStream_t stream) {
    const float* x  = (const float*)d_in[0];
    const int*   ei = (const int*)d_in[1];
    const float* W  = (const float*)d_in[2];
    float* out = (float*)d_out;

    const int N = in_sizes[0] / C;
    const int E = in_sizes[1] / 2;
    const int* rowI = ei;        // edge_index[0]
    const int* colI = ei + E;    // edge_index[1]

    const int NB = (N + BWIDTH - 1) / BWIDTH;     // 196 for N=100000

    // workspace carve-up (256B-aligned regions)
    char* ws = (char*)d_ws;
    size_t off = 0;
    auto carve = [&](size_t bytes) -> void* {
        off = (off + 255) & ~(size_t)255;
        void* p = ws + off;
        off += bytes;
        return p;
    };
    int*      gcur       = (int*)carve((size_t)NBMAX * 4);
    int*      offs_start = (int*)carve((size_t)N * 4);
    int*      offs_end   = (int*)carve((size_t)N * 4);
    float*    inv        = (float*)carve((size_t)N * 4);
    int*      csr        = (int*)carve((size_t)NB * CAP * 4);
    __half2*  xh         = (__half2*)carve((size_t)N * C * 2);
    unsigned* ebuf       = (unsigned*)carve((size_t)NB * CAP * 4);
    __half2*  Wh         = (__half2*)carve((size_t)C * C * 2);

    hipMemsetAsync(gcur, 0, (size_t)NBMAX * 4, stream);

    int wtotal4 = C * C / 4;                  // 4096 float4
    int nChunks = (E + P2CHUNK - 1) / P2CHUNK;
    p2_scatter_kernel<<<nChunks, 512, 0, stream>>>(rowI, colI, gcur, ebuf, E,
                                                   (const float4*)x, xh, N,
                                                   (const float4*)W, Wh, wtotal4);
    p3_place_kernel<<<NB, 512, 0, stream>>>(ebuf, gcur, offs_start, offs_end, inv, csr, N);

    gather_mm_kernel<<<(N + 15) / 16, 256, 0, stream>>>((const float4*)xh, offs_start,
                                                        offs_end, csr, inv,
                                                        (const _Float16*)Wh, out, N);
}

// Round 17
// 117.293 us; speedup vs baseline: 1.1254x; 1.0621x over previous
//
#include <hip/hip_runtime.h>
#include <hip/hip_fp16.h>
#include <math.h>

#define C 128
#define BSHIFT 9        // bucket width = 512 nodes
#define BWIDTH 512
#define NBMAX 256       // >= ceil(100000/512)=196
#define COLBITS 17      // N=100000 < 2^17; ebuf packs (lrow<<17)|col
#define P2CHUNK 8192    // edges per p2 sort block (16/thread, 512 threads)
#define P3CAP 10240     // LDS staging capacity for one bucket (max count ~8500)
#define CAP 9216        // fixed per-bucket segment capacity (mean 8192 + 11.6 sigma)
#define APITCH 136      // fp16 pitch for LDS agg tile: 272B rows -> 2-way conflicts (free)

typedef _Float16 v8hf __attribute__((ext_vector_type(8)));
typedef float v4f __attribute__((ext_vector_type(4)));

// ---- 1. scatter edges into bucket-segmented ebuf (LDS sort, blocks < nSort)
//      + x/W->fp16 grid-stride conversion (ALL blocks; extra blocks convert only).
// gcur starts 0 (memset); segment base = b*CAP + old cursor; gcur ends = count.
__global__ __launch_bounds__(512) void p2_scatter_kernel(const int* __restrict__ rowI,
                                                         const int* __restrict__ colI,
                                                         int* __restrict__ gcur,
                                                         unsigned* __restrict__ ebuf, int E,
                                                         int nSort,
                                                         const float4* __restrict__ x4,
                                                         __half2* __restrict__ xh2, int N,
                                                         const float4* __restrict__ W4,
                                                         __half2* __restrict__ Wh2,
                                                         int wtotal4) {
    __shared__ int cnt[NBMAX];
    __shared__ int sc[NBMAX];                 // scan -> reused as lstart
    __shared__ int delta[NBMAX];              // global base - lstart
    __shared__ unsigned sorted[P2CHUNK];      // 32 KB
    __shared__ unsigned char bkt[P2CHUNK];    // 8 KB
    const int t = threadIdx.x;
    if (blockIdx.x < nSort) {
        if (t < NBMAX) cnt[t] = 0;
        __syncthreads();
        const int e0 = blockIdx.x * P2CHUNK;
        int ranks[16];
#pragma unroll
        for (int k = 0; k < 16; ++k) {
            int e = e0 + k * 512 + t;
            if (e < E) ranks[k] = atomicAdd(&cnt[rowI[e] >> BSHIFT], 1);
        }
        __syncthreads();
        if (t < NBMAX) sc[t] = cnt[t];
        __syncthreads();
        for (int o = 1; o < NBMAX; o <<= 1) { // Hillis-Steele inclusive (guarded)
            int v = (t < NBMAX && t >= o) ? sc[t - o] : 0;
            __syncthreads();
            if (t < NBMAX) sc[t] += v;
            __syncthreads();
        }
        if (t < NBMAX) {
            int c = cnt[t];
            int ls = sc[t] - c;               // local exclusive start
            int gb = c ? (t * CAP + atomicAdd(&gcur[t], c)) : 0;
            delta[t] = gb - ls;
            sc[t] = ls;                       // sc now holds lstart
        }
        __syncthreads();
#pragma unroll
        for (int k = 0; k < 16; ++k) {
            int e = e0 + k * 512 + t;
            if (e < E) {
                int r = rowI[e];              // L1/L2-hot re-read
                unsigned cc = (unsigned)colI[e];
                int b = r >> BSHIFT;
                int lp = sc[b] + ranks[k];
                sorted[lp] = ((unsigned)(r & (BWIDTH - 1)) << COLBITS) | cc;
                bkt[lp] = (unsigned char)b;
            }
        }
        __syncthreads();
        int total = E - e0; if (total > P2CHUNK) total = P2CHUNK;
#pragma unroll
        for (int k = 0; k < 16; ++k) {        // linear LDS -> coalesced global runs
            int i = k * 512 + t;
            if (i < total) ebuf[delta[bkt[i]] + i] = sorted[i];
        }
    }

    // ---- fused x -> fp16 (UNSCALED) and W -> fp16 (grid-stride, all blocks) ----
    int totalX4 = N * 32;                     // 32 float4 per row
    int totalConv = totalX4 + wtotal4;
    for (int i = blockIdx.x * 512 + t; i < totalConv; i += gridDim.x * 512) {
        if (i < totalX4) {
            float4 v = x4[i];
            xh2[i * 2]     = __floats2half2_rn(v.x, v.y);
            xh2[i * 2 + 1] = __floats2half2_rn(v.z, v.w);
        } else {
            int j = i - totalX4;
            float4 v = W4[j];
            Wh2[j * 2]     = __floats2half2_rn(v.x, v.y);
            Wh2[j * 2 + 1] = __floats2half2_rn(v.z, v.w);
        }
    }
}

// ---- 2. per-bucket place: LDS-staged segment, wave-scan, csr stream ----
// NB(196) < 256 CUs -> 1 block/CU; ~82KB LDS is free here.
// Emits offs_start/offs_end[node], inv[node] = rsqrt(deg+1), csr.
__global__ __launch_bounds__(512) void p3_place_kernel(const unsigned* __restrict__ ebuf,
                                                       const int* __restrict__ gcur,
                                                       int* __restrict__ offs_start,
                                                       int* __restrict__ offs_end,
                                                       float* __restrict__ inv,
                                                       int* __restrict__ csr, int N) {
    __shared__ unsigned eb[P3CAP];            // 40 KB staged segment
    __shared__ int sortedCol[P3CAP];          // 40 KB
    __shared__ int cnt[BWIDTH];
    __shared__ int woff[8];
    const int b = blockIdx.x;
    const int t = threadIdx.x;
    const int lane = t & 63;
    const int wv = t >> 6;
    const int rowBase = b << BSHIFT;
    const int eS = b * CAP;
    int len = gcur[b];                        // bucket count (<= CAP < P3CAP)
    if (len > P3CAP) len = P3CAP;

    cnt[t] = 0;
    __syncthreads();
    for (int i = t; i < len; i += 512) {      // stage + histogram, single global read
        unsigned rc = ebuf[eS + i];
        eb[i] = rc;
        atomicAdd(&cnt[rc >> COLBITS], 1);
    }
    __syncthreads();
    int myCnt = cnt[t];
    int v = myCnt;                            // wave-inclusive scan (shfl_up)
#pragma unroll
    for (int o = 1; o < 64; o <<= 1) {
        int u = __shfl_up(v, o, 64);
        if (lane >= o) v += u;
    }
    if (lane == 63) woff[wv] = v;
    __syncthreads();
    if (t == 0) {                             // serial scan of 8 wave totals
        int s = 0;
#pragma unroll
        for (int w = 0; w < 8; ++w) { int u = woff[w]; woff[w] = s; s += u; }
    }
    __syncthreads();
    int incl = v + woff[wv];                  // inclusive prefix over 512 bins
    int node = rowBase + t;
    if (node < N) {
        offs_start[node] = eS + incl - myCnt;
        offs_end[node]   = eS + incl;
        inv[node] = rsqrtf((float)myCnt + 1.0f);
    }
    cnt[t] = incl - myCnt;                    // local exclusive start -> cursor
    __syncthreads();
    for (int i = t; i < len; i += 512) {
        unsigned rc = eb[i];
        int slot = atomicAdd(&cnt[rc >> COLBITS], 1);
        sortedCol[slot] = (int)(rc & ((1u << COLBITS) - 1));
    }
    __syncthreads();
    for (int i = t; i < len; i += 512)        // pure streaming write
        csr[eS + i] = sortedCol[i];
}

// ---- 3. fused gather + MFMA GEMM (256 thr = 16 nodes x 16 lanes) ----
// Phase 1: a += inv[c] * xh[c] per edge (fmaf); scale by inv[n]; fp16 row ->
// LDS agg. Phase 2: 4 waves compute out[16][128] = agg @ Wh^T (16x16x32 f16).
// A lane: row=l&15, k=(l>>4)*8+i (+kk*32); D: col=lane&15, row=(lane>>4)*4+reg.
#define ACC4F(vv, sI)                                              \
    {                                                              \
        const __half2* p_ = (const __half2*)&(vv);                 \
        _Pragma("unroll")                                          \
        for (int q = 0; q < 4; ++q) {                              \
            float2 f_ = __half22float2(p_[q]);                     \
            a[2 * q]     = fmaf(f_.x, (sI), a[2 * q]);             \
            a[2 * q + 1] = fmaf(f_.y, (sI), a[2 * q + 1]);         \
        }                                                          \
    }

__global__ __launch_bounds__(256, 8) void gather_mm_kernel(const float4* __restrict__ xh4,
                                                           const int* __restrict__ offs_start,
                                                           const int* __restrict__ offs_end,
                                                           const int* __restrict__ csr,
                                                           const float* __restrict__ inv,
                                                           const _Float16* __restrict__ Wh,
                                                           float* __restrict__ out, int N) {
    __shared__ _Float16 agg[16][APITCH];      // 4.25 KB
    const int tid = threadIdx.x;
    const int base = blockIdx.x * 16;
    const int r = tid >> 4;                   // block-local node 0..15
    const int c16 = tid & 15;                 // 16B chunk within row
    const int node = base + r;

    float a[8] = {0, 0, 0, 0, 0, 0, 0, 0};
    float invn = 0.0f;
    if (node < N) {
        int s = offs_start[node];
        int e = offs_end[node];
        invn = inv[node];
        {   // self term
            float4 h = xh4[(size_t)node * 16 + c16];
            ACC4F(h, invn)
        }
        int j = s;
        for (; j + 4 <= e; j += 4) {
            int c0 = csr[j], c1 = csr[j + 1], c2 = csr[j + 2], c3 = csr[j + 3];
            float i0 = inv[c0], i1 = inv[c1], i2 = inv[c2], i3 = inv[c3];
            float4 v0 = xh4[(size_t)c0 * 16 + c16];
            float4 v1 = xh4[(size_t)c1 * 16 + c16];
            float4 v2 = xh4[(size_t)c2 * 16 + c16];
            float4 v3 = xh4[(size_t)c3 * 16 + c16];
            ACC4F(v0, i0) ACC4F(v1, i1) ACC4F(v2, i2) ACC4F(v3, i3)
        }
        for (; j < e; ++j) {
            int c = csr[j];
            float ic = inv[c];
            float4 v = xh4[(size_t)c * 16 + c16];
            ACC4F(v, ic)
        }
#pragma unroll
        for (int q = 0; q < 8; ++q) a[q] *= invn;
    }
    {
        __half2 hh[4];
#pragma unroll
        for (int q = 0; q < 4; ++q) hh[q] = __floats2half2_rn(a[2 * q], a[2 * q + 1]);
        *(float4*)&agg[r][c16 * 8] = *(const float4*)hh;   // 16B, 2-way banks (free)
    }
    __syncthreads();

    // ---- MFMA phase: wave w computes col-tiles t = 2w, 2w+1 ----
    const int wave = tid >> 6;
    const int lane = tid & 63;
    const int rr = lane & 15;
    const int kg = lane >> 4;

    v8hf av[4];
#pragma unroll
    for (int kk = 0; kk < 4; ++kk)
        av[kk] = *(const v8hf*)&agg[rr][kg * 8 + kk * 32];

#pragma unroll
    for (int ti = 0; ti < 2; ++ti) {
        const int t = wave * 2 + ti;
        v4f acc = {0.0f, 0.0f, 0.0f, 0.0f};
        const v8hf* bp = (const v8hf*)(Wh + (size_t)(t * 16 + rr) * C + kg * 8);
#pragma unroll
        for (int kk = 0; kk < 4; ++kk)
            acc = __builtin_amdgcn_mfma_f32_16x16x32_f16(av[kk], bp[kk * 4], acc, 0, 0, 0);
#pragma unroll
        for (int reg = 0; reg < 4; ++reg) {
            int orow = base + kg * 4 + reg;
            if (orow < N) out[(size_t)orow * C + t * 16 + rr] = acc[reg];
        }
    }
}

extern "C" void kernel_launch(void* const* d_in, const int* in_sizes, int n_in,
                              void* d_out, int out_size, void* d_ws, size_t ws_size,
                              hipStream_t stream) {
    const float* x  = (const float*)d_in[0];
    const int*   ei = (const int*)d_in[1];
    const float* W  = (const float*)d_in[2];
    float* out = (float*)d_out;

    const int N = in_sizes[0] / C;
    const int E = in_sizes[1] / 2;
    const int* rowI = ei;        // edge_index[0]
    const int* colI = ei + E;    // edge_index[1]

    const int NB = (N + BWIDTH - 1) / BWIDTH;     // 196 for N=100000

    // workspace carve-up (256B-aligned regions)
    char* ws = (char*)d_ws;
    size_t off = 0;
    auto carve = [&](size_t bytes) -> void* {
        off = (off + 255) & ~(size_t)255;
        void* p = ws + off;
        off += bytes;
        return p;
    };
    int*      gcur       = (int*)carve((size_t)NBMAX * 4);
    int*      offs_start = (int*)carve((size_t)N * 4);
    int*      offs_end   = (int*)carve((size_t)N * 4);
    float*    inv        = (float*)carve((size_t)N * 4);
    int*      csr        = (int*)carve((size_t)NB * CAP * 4);
    __half2*  xh         = (__half2*)carve((size_t)N * C * 2);
    unsigned* ebuf       = (unsigned*)carve((size_t)NB * CAP * 4);
    __half2*  Wh         = (__half2*)carve((size_t)C * C * 2);

    hipMemsetAsync(gcur, 0, (size_t)NBMAX * 4, stream);

    int wtotal4 = C * C / 4;                  // 4096 float4
    int nSort = (E + P2CHUNK - 1) / P2CHUNK;  // 196
    int nGrid = nSort * 2;                    // extra blocks convert only
    p2_scatter_kernel<<<nGrid, 512, 0, stream>>>(rowI, colI, gcur, ebuf, E, nSort,
                                                 (const float4*)x, xh, N,
                                                 (const float4*)W, Wh, wtotal4);
    p3_place_kernel<<<NB, 512, 0, stream>>>(ebuf, gcur, offs_start, offs_end, inv, csr, N);

    gather_mm_kernel<<<(N + 15) / 16, 256, 0, stream>>>((const float4*)xh, offs_start,
                                                        offs_end, csr, inv,
                                                        (const _Float16*)Wh, out, N);
}

// Round 18
// 114.469 us; speedup vs baseline: 1.1532x; 1.0247x over previous
//
#include <hip/hip_runtime.h>
#include <hip/hip_fp16.h>
#include <math.h>

#define C 128
#define BSHIFT 9        // bucket width = 512 nodes
#define BWIDTH 512
#define NBMAX 256       // >= ceil(100000/512)=196
#define COLBITS 17      // N=100000 < 2^17; ebuf packs (lrow<<17)|col
#define P2CHUNK 8192    // edges per p2 sort block (16/thread, 512 threads)
#define P3CAP 10240     // LDS staging capacity for one bucket (max count ~8500)
#define CAP 9216        // fixed per-bucket segment capacity (mean 8192 + 11.6 sigma)
#define APITCH 136      // fp16 pitch for LDS agg tile: 272B rows -> 2-way conflicts (free)

typedef _Float16 v8hf __attribute__((ext_vector_type(8)));
typedef float v4f __attribute__((ext_vector_type(4)));

// ---- 1. scatter edges into bucket-segmented ebuf (LDS sort, blocks < nSort)
//      + x/W->fp16 grid-stride conversion (ALL blocks; extra blocks convert only).
// gcur starts 0 (memset); segment base = b*CAP + old cursor; gcur ends = count.
// Edge data (packed value + bucket id) is register-cached in the rank pass so
// the LDS-write pass does no global reads.
__global__ __launch_bounds__(512) void p2_scatter_kernel(const int* __restrict__ rowI,
                                                         const int* __restrict__ colI,
                                                         int* __restrict__ gcur,
                                                         unsigned* __restrict__ ebuf, int E,
                                                         int nSort,
                                                         const float4* __restrict__ x4,
                                                         __half2* __restrict__ xh2, int N,
                                                         const float4* __restrict__ W4,
                                                         __half2* __restrict__ Wh2,
                                                         int wtotal4) {
    __shared__ int cnt[NBMAX];
    __shared__ int sc[NBMAX];                 // scan -> reused as lstart
    __shared__ int delta[NBMAX];              // global base - lstart
    __shared__ unsigned sorted[P2CHUNK];      // 32 KB
    __shared__ unsigned char bkt[P2CHUNK];    // 8 KB
    const int t = threadIdx.x;
    if (blockIdx.x < nSort) {
        if (t < NBMAX) cnt[t] = 0;
        __syncthreads();
        const int e0 = blockIdx.x * P2CHUNK;
        int ranks[16];
        unsigned pk[16];                      // packed (lrow<<17)|col
        short bk[16];                         // bucket id
#pragma unroll
        for (int k = 0; k < 16; ++k) {
            int e = e0 + k * 512 + t;
            if (e < E) {
                int r = rowI[e];
                unsigned cc = (unsigned)colI[e];
                int b = r >> BSHIFT;
                pk[k] = ((unsigned)(r & (BWIDTH - 1)) << COLBITS) | cc;
                bk[k] = (short)b;
                ranks[k] = atomicAdd(&cnt[b], 1);
            }
        }
        __syncthreads();
        if (t < NBMAX) sc[t] = cnt[t];
        __syncthreads();
        for (int o = 1; o < NBMAX; o <<= 1) { // Hillis-Steele inclusive (guarded)
            int v = (t < NBMAX && t >= o) ? sc[t - o] : 0;
            __syncthreads();
            if (t < NBMAX) sc[t] += v;
            __syncthreads();
        }
        if (t < NBMAX) {
            int c = cnt[t];
            int ls = sc[t] - c;               // local exclusive start
            int gb = c ? (t * CAP + atomicAdd(&gcur[t], c)) : 0;
            delta[t] = gb - ls;
            sc[t] = ls;                       // sc now holds lstart
        }
        __syncthreads();
#pragma unroll
        for (int k = 0; k < 16; ++k) {        // no global reads: all from regs
            int e = e0 + k * 512 + t;
            if (e < E) {
                int b = bk[k];
                int lp = sc[b] + ranks[k];
                sorted[lp] = pk[k];
                bkt[lp] = (unsigned char)b;
            }
        }
        __syncthreads();
        int total = E - e0; if (total > P2CHUNK) total = P2CHUNK;
#pragma unroll
        for (int k = 0; k < 16; ++k) {        // linear LDS -> coalesced global runs
            int i = k * 512 + t;
            if (i < total) ebuf[delta[bkt[i]] + i] = sorted[i];
        }
    }

    // ---- fused x -> fp16 (UNSCALED) and W -> fp16 (grid-stride, all blocks) ----
    int totalX4 = N * 32;                     // 32 float4 per row
    int totalConv = totalX4 + wtotal4;
    for (int i = blockIdx.x * 512 + t; i < totalConv; i += gridDim.x * 512) {
        if (i < totalX4) {
            float4 v = x4[i];
            xh2[i * 2]     = __floats2half2_rn(v.x, v.y);
            xh2[i * 2 + 1] = __floats2half2_rn(v.z, v.w);
        } else {
            int j = i - totalX4;
            float4 v = W4[j];
            Wh2[j * 2]     = __floats2half2_rn(v.x, v.y);
            Wh2[j * 2 + 1] = __floats2half2_rn(v.z, v.w);
        }
    }
}

// ---- 2. per-bucket place: LDS-staged segment, wave-scan, csr stream ----
// NB(196) < 256 CUs -> 1 block/CU; ~82KB LDS is free here.
// Emits offs_start/offs_end[node], inv[node] = rsqrt(deg+1), csr.
__global__ __launch_bounds__(512) void p3_place_kernel(const unsigned* __restrict__ ebuf,
                                                       const int* __restrict__ gcur,
                                                       int* __restrict__ offs_start,
                                                       int* __restrict__ offs_end,
                                                       float* __restrict__ inv,
                                                       int* __restrict__ csr, int N) {
    __shared__ unsigned eb[P3CAP];            // 40 KB staged segment
    __shared__ int sortedCol[P3CAP];          // 40 KB
    __shared__ int cnt[BWIDTH];
    __shared__ int woff[8];
    const int b = blockIdx.x;
    const int t = threadIdx.x;
    const int lane = t & 63;
    const int wv = t >> 6;
    const int rowBase = b << BSHIFT;
    const int eS = b * CAP;
    int len = gcur[b];                        // bucket count (<= CAP < P3CAP)
    if (len > P3CAP) len = P3CAP;

    cnt[t] = 0;
    __syncthreads();
    for (int i = t; i < len; i += 512) {      // stage + histogram, single global read
        unsigned rc = ebuf[eS + i];
        eb[i] = rc;
        atomicAdd(&cnt[rc >> COLBITS], 1);
    }
    __syncthreads();
    int myCnt = cnt[t];
    int v = myCnt;                            // wave-inclusive scan (shfl_up)
#pragma unroll
    for (int o = 1; o < 64; o <<= 1) {
        int u = __shfl_up(v, o, 64);
        if (lane >= o) v += u;
    }
    if (lane == 63) woff[wv] = v;
    __syncthreads();
    if (t == 0) {                             // serial scan of 8 wave totals
        int s = 0;
#pragma unroll
        for (int w = 0; w < 8; ++w) { int u = woff[w]; woff[w] = s; s += u; }
    }
    __syncthreads();
    int incl = v + woff[wv];                  // inclusive prefix over 512 bins
    int node = rowBase + t;
    if (node < N) {
        offs_start[node] = eS + incl - myCnt;
        offs_end[node]   = eS + incl;
        inv[node] = rsqrtf((float)myCnt + 1.0f);
    }
    cnt[t] = incl - myCnt;                    // local exclusive start -> cursor
    __syncthreads();
    for (int i = t; i < len; i += 512) {
        unsigned rc = eb[i];
        int slot = atomicAdd(&cnt[rc >> COLBITS], 1);
        sortedCol[slot] = (int)(rc & ((1u << COLBITS) - 1));
    }
    __syncthreads();
    for (int i = t; i < len; i += 512)        // pure streaming write
        csr[eS + i] = sortedCol[i];
}

// ---- 3. fused gather + MFMA GEMM (256 thr = 16 nodes x 16 lanes) ----
// Phase 1: a += inv[c] * xh[c] per edge (fmaf); scale by inv[n]; fp16 row ->
// LDS agg. Phase 2: 4 waves compute out[16][128] = agg @ Wh^T (16x16x32 f16).
// A lane: row=l&15, k=(l>>4)*8+i (+kk*32); D: col=lane&15, row=(lane>>4)*4+reg.
#define ACC4F(vv, sI)                                              \
    {                                                              \
        const __half2* p_ = (const __half2*)&(vv);                 \
        _Pragma("unroll")                                          \
        for (int q = 0; q < 4; ++q) {                              \
            float2 f_ = __half22float2(p_[q]);                     \
            a[2 * q]     = fmaf(f_.x, (sI), a[2 * q]);             \
            a[2 * q + 1] = fmaf(f_.y, (sI), a[2 * q + 1]);         \
        }                                                          \
    }

__global__ __launch_bounds__(256, 8) void gather_mm_kernel(const float4* __restrict__ xh4,
                                                           const int* __restrict__ offs_start,
                                                           const int* __restrict__ offs_end,
                                                           const int* __restrict__ csr,
                                                           const float* __restrict__ inv,
                                                           const _Float16* __restrict__ Wh,
                                                           float* __restrict__ out, int N) {
    __shared__ _Float16 agg[16][APITCH];      // 4.25 KB
    const int tid = threadIdx.x;
    const int base = blockIdx.x * 16;
    const int r = tid >> 4;                   // block-local node 0..15
    const int c16 = tid & 15;                 // 16B chunk within row
    const int node = base + r;

    float a[8] = {0, 0, 0, 0, 0, 0, 0, 0};
    float invn = 0.0f;
    if (node < N) {
        int s = offs_start[node];
        int e = offs_end[node];
        invn = inv[node];
        {   // self term
            float4 h = xh4[(size_t)node * 16 + c16];
            ACC4F(h, invn)
        }
        int j = s;
        for (; j + 4 <= e; j += 4) {
            int c0 = csr[j], c1 = csr[j + 1], c2 = csr[j + 2], c3 = csr[j + 3];
            float i0 = inv[c0], i1 = inv[c1], i2 = inv[c2], i3 = inv[c3];
            float4 v0 = xh4[(size_t)c0 * 16 + c16];
            float4 v1 = xh4[(size_t)c1 * 16 + c16];
            float4 v2 = xh4[(size_t)c2 * 16 + c16];
            float4 v3 = xh4[(size_t)c3 * 16 + c16];
            ACC4F(v0, i0) ACC4F(v1, i1) ACC4F(v2, i2) ACC4F(v3, i3)
        }
        for (; j < e; ++j) {
            int c = csr[j];
            float ic = inv[c];
            float4 v = xh4[(size_t)c * 16 + c16];
            ACC4F(v, ic)
        }
#pragma unroll
        for (int q = 0; q < 8; ++q) a[q] *= invn;
    }
    {
        __half2 hh[4];
#pragma unroll
        for (int q = 0; q < 4; ++q) hh[q] = __floats2half2_rn(a[2 * q], a[2 * q + 1]);
        *(float4*)&agg[r][c16 * 8] = *(const float4*)hh;   // 16B, 2-way banks (free)
    }
    __syncthreads();

    // ---- MFMA phase: wave w computes col-tiles t = 2w, 2w+1 ----
    const int wave = tid >> 6;
    const int lane = tid & 63;
    const int rr = lane & 15;
    const int kg = lane >> 4;

    v8hf av[4];
#pragma unroll
    for (int kk = 0; kk < 4; ++kk)
        av[kk] = *(const v8hf*)&agg[rr][kg * 8 + kk * 32];

#pragma unroll
    for (int ti = 0; ti < 2; ++ti) {
        const int t = wave * 2 + ti;
        v4f acc = {0.0f, 0.0f, 0.0f, 0.0f};
        const v8hf* bp = (const v8hf*)(Wh + (size_t)(t * 16 + rr) * C + kg * 8);
#pragma unroll
        for (int kk = 0; kk < 4; ++kk)
            acc = __builtin_amdgcn_mfma_f32_16x16x32_f16(av[kk], bp[kk * 4], acc, 0, 0, 0);
#pragma unroll
        for (int reg = 0; reg < 4; ++reg) {
            int orow = base + kg * 4 + reg;
            if (orow < N) out[(size_t)orow * C + t * 16 + rr] = acc[reg];
        }
    }
}

extern "C" void kernel_launch(void* const* d_in, const int* in_sizes, int n_in,
                              void* d_out, int out_size, void* d_ws, size_t ws_size,
                              hipStream_t stream) {
    const float* x  = (const float*)d_in[0];
    const int*   ei = (const int*)d_in[1];
    const float* W  = (const float*)d_in[2];
    float* out = (float*)d_out;

    const int N = in_sizes[0] / C;
    const int E = in_sizes[1] / 2;
    const int* rowI = ei;        // edge_index[0]
    const int* colI = ei + E;    // edge_index[1]

    const int NB = (N + BWIDTH - 1) / BWIDTH;     // 196 for N=100000

    // workspace carve-up (256B-aligned regions)
    char* ws = (char*)d_ws;
    size_t off = 0;
    auto carve = [&](size_t bytes) -> void* {
        off = (off + 255) & ~(size_t)255;
        void* p = ws + off;
        off += bytes;
        return p;
    };
    int*      gcur       = (int*)carve((size_t)NBMAX * 4);
    int*      offs_start = (int*)carve((size_t)N * 4);
    int*      offs_end   = (int*)carve((size_t)N * 4);
    float*    inv        = (float*)carve((size_t)N * 4);
    int*      csr        = (int*)carve((size_t)NB * CAP * 4);
    __half2*  xh         = (__half2*)carve((size_t)N * C * 2);
    unsigned* ebuf       = (unsigned*)carve((size_t)NB * CAP * 4);
    __half2*  Wh         = (__half2*)carve((size_t)C * C * 2);

    hipMemsetAsync(gcur, 0, (size_t)NBMAX * 4, stream);

    int wtotal4 = C * C / 4;                  // 4096 float4
    int nSort = (E + P2CHUNK - 1) / P2CHUNK;  // 196
    int nGrid = nSort * 2;                    // extra blocks convert only
    p2_scatter_kernel<<<nGrid, 512, 0, stream>>>(rowI, colI, gcur, ebuf, E, nSort,
                                                 (const float4*)x, xh, N,
                                                 (const float4*)W, Wh, wtotal4);
    p3_place_kernel<<<NB, 512, 0, stream>>>(ebuf, gcur, offs_start, offs_end, inv, csr, N);

    gather_mm_kernel<<<(N + 15) / 16, 256, 0, stream>>>((const float4*)xh, offs_start,
                                                        offs_end, csr, inv,
                                                        (const _Float16*)Wh, out, N);
}